// Round 20
// baseline (39.141 us; speedup 1.0000x reference)
//
#include <hip/hip_runtime.h>
#include <stdint.h>

#define NB 4096
#define QLEN 1024
#define NL 64
#define KLEN 32
#define NS (QLEN - KLEN + 1)   // 993
#define WSLICE 1864            // u32 per wave slice: pkE 544 | pkO 544 | nwh 512 | s4 264

typedef __attribute__((ext_vector_type(8)))  _Float16 half8;
typedef __attribute__((ext_vector_type(16))) float    f32x16;

union frag4 { uint4 q; half8 v; uint32_t u[4]; };

static __device__ __forceinline__ uint32_t pkh(float a, float b) {
    return __builtin_bit_cast(uint32_t, __builtin_amdgcn_cvt_pkrtz(a, b)); // v_cvt_pkrtz_f16_f32
}
static __device__ __forceinline__ float lo16f(uint32_t w) {
    return (float)__builtin_bit_cast(_Float16, (unsigned short)(w & 0xFFFFu));
}
static __device__ __forceinline__ float hi16f(uint32_t w) {
    return (float)__builtin_bit_cast(_Float16, (unsigned short)(w >> 16));
}
static __device__ __forceinline__ uint32_t pkh_rne(float a, float b) {  // RNE f16 pair
    unsigned short ha = __builtin_bit_cast(unsigned short, (_Float16)a);
    unsigned short hb = __builtin_bit_cast(unsigned short, (_Float16)b);
    return (uint32_t)ha | ((uint32_t)hb << 16);
}

__global__ __launch_bounds__(256, 4) void shapelet_r20(
    const float* __restrict__ ts,        // [B, Q]
    const float* __restrict__ shapelets, // [L, K]
    const float* __restrict__ fc_w,      // [2, L]
    const float* __restrict__ fc_b,      // [2]
    float* __restrict__ out)             // [B, 2]
{
    // 4 private slices, one per wave; NO __syncthreads (r12 autonomy).
    __shared__ __align__(16) uint32_t lds[4 * WSLICE];   // 29.8 KB

    const int tid  = threadIdx.x;
    const int wave = tid >> 6;
    const int lane = tid & 63;
    const int l31  = lane & 31;          // shapelet / A-row index
    const int hk   = lane >> 5;          // k-half-group (0,1)
    const int row  = blockIdx.x * 4 + wave;

    uint32_t* pkE = lds + wave * WSLICE;                   // [544]
    uint32_t* pkO = pkE + 544;                             // [544]
    uint32_t* nwh = pkO + 544;                             // [512] -0.5*win f16, permuted
    float*    s4  = reinterpret_cast<float*>(nwh + 512);   // [264]

    // --- pass 1: wave loads its row, packs f16 phase-pairs, 4-square partials ---
    const float* rowp = ts + (size_t)row * QLEN;
    float4 v[4];
    float  x4[4];
    #pragma unroll
    for (int c = 0; c < 4; ++c)
        v[c] = reinterpret_cast<const float4*>(rowp)[64 * c + lane];
    #pragma unroll
    for (int c = 0; c < 4; ++c) {
        const int p = 256 * c + 4 * lane + 4;
        x4[c] = (p < QLEN) ? rowp[p] : 0.0f;
    }
    #pragma unroll
    for (int c = 0; c < 4; ++c) {
        uint2 pe = { pkh(v[c].x, v[c].y), pkh(v[c].z, v[c].w) };
        uint2 po = { pkh(v[c].y, v[c].z), pkh(v[c].w, x4[c]) };
        reinterpret_cast<uint2*>(pkE)[64 * c + lane] = pe;
        reinterpret_cast<uint2*>(pkO)[64 * c + lane] = po;
        s4[64 * c + lane] =
            fmaf(v[c].x, v[c].x, fmaf(v[c].y, v[c].y, fmaf(v[c].z, v[c].z, v[c].w * v[c].w)));
    }
    if (lane < 32) { pkE[512 + lane] = 0u; pkO[512 + lane] = 0u; }
    if (lane < 8)  s4[256 + lane] = 0.0f;

    // --- B fragments (fp16 RTZ), 32x32x16 layout: lane holds sh[l31][hk*8+e]
    //     (kh=0) and sh[l31][16+hk*8+e] (kh=1), for 2 l-tiles of 32 ---
    frag4 Bf[2][2];   // [lt][kh]
    float ssq[2];
    #pragma unroll
    for (int lt = 0; lt < 2; ++lt) {
        float s = 0.0f;
        #pragma unroll
        for (int kh = 0; kh < 2; ++kh) {
            const float* sp = shapelets + (lt * 32 + l31) * KLEN + kh * 16 + hk * 8;
            float4 f0 = *reinterpret_cast<const float4*>(sp);
            float4 f1 = *reinterpret_cast<const float4*>(sp + 4);
            Bf[lt][kh].u[0] = pkh(f0.x, f0.y);
            Bf[lt][kh].u[1] = pkh(f0.z, f0.w);
            Bf[lt][kh].u[2] = pkh(f1.x, f1.y);
            Bf[lt][kh].u[3] = pkh(f1.z, f1.w);
            s = fmaf(f0.x, f0.x, s); s = fmaf(f0.y, f0.y, s);
            s = fmaf(f0.z, f0.z, s); s = fmaf(f0.w, f0.w, s);
            s = fmaf(f1.x, f1.x, s); s = fmaf(f1.y, f1.y, s);
            s = fmaf(f1.z, f1.z, s); s = fmaf(f1.w, f1.w, s);
        }
        ssq[lt] = s;   // covers 16 of 32 k; other half in lane^32
    }

    __builtin_amdgcn_wave_barrier();   // pass-1 writes before pass-2 reads

    // --- pass 2: win_sq + f16 corrections -> nwh in 32x32 C-layout order:
    //     tile t word-idx = h'*8 + g*2 + ph  (row = 8g + 4h' + 2ph + {0,1}) ---
    #pragma unroll
    for (int c = 0; c < 4; ++c) {
        const int q = 64 * c + lane;
        float s_[8];
        #pragma unroll
        for (int j = 0; j < 8; ++j) s_[j] = s4[q + j];
        float w0 = ((s_[0] + s_[1]) + (s_[2] + s_[3])) + ((s_[4] + s_[5]) + (s_[6] + s_[7]));
        uint32_t cw0 = pkE[2 * (q + 8)];
        uint32_t cw1 = pkE[2 * (q + 8) + 1];
        float x32 = lo16f(cw0), x33 = hi16f(cw0), x34 = lo16f(cw1);
        float w1 = fmaf(x32, x32, fmaf(-v[c].x, v[c].x, w0));
        float w2 = fmaf(x33, x33, fmaf(-v[c].y, v[c].y, w1));
        float w3 = fmaf(x34, x34, fmaf(-v[c].z, v[c].z, w2));
        const int p0 = 4 * q;
        float c0 = (p0 + 0 < NS) ? -0.5f * w0 : -60000.0f;
        float c1 = (p0 + 1 < NS) ? -0.5f * w1 : -60000.0f;
        float c2 = (p0 + 2 < NS) ? -0.5f * w2 : -60000.0f;
        float c3 = (p0 + 3 < NS) ? -0.5f * w3 : -60000.0f;
        const int W = 16 * (p0 >> 5) + ((p0 >> 2) & 1) * 8 + ((p0 >> 3) & 3) * 2;
        uint2 hw = { pkh_rne(c0, c1), pkh_rne(c2, c3) };
        *reinterpret_cast<uint2*>(&nwh[W]) = hw;
    }

    __builtin_amdgcn_wave_barrier();   // pass-2 stores before main-loop reads

    // --- main loop: 32 position-tiles of 32; per tile: 2 l-tiles x 2 k-half
    //     MFMAs (32x32x16, accumulating), rmax in C-layout (16 regs per lt) ---
    float rmax[2][16];
    #pragma unroll
    for (int lt = 0; lt < 2; ++lt)
        #pragma unroll
        for (int e = 0; e < 16; ++e) rmax[lt][e] = -3.0e38f;

    const int par = l31 & 1;
    const uint32_t* apk = (par ? pkO : pkE) + (((l31 - par) >> 1) + hk * 4);
    const int nwb = hk * 8;

    #pragma unroll 1
    for (int t = 0; t < 32; ++t) {
        const uint32_t* ap = apk + 16 * t;
        frag4 A1, A2;
        #pragma unroll
        for (int j = 0; j < 4; ++j) A1.u[j] = ap[j];
        #pragma unroll
        for (int j = 0; j < 4; ++j) A2.u[j] = ap[8 + j];
        uint4 nw0 = *reinterpret_cast<const uint4*>(&nwh[16 * t + nwb]);
        uint4 nw1 = *reinterpret_cast<const uint4*>(&nwh[16 * t + nwb + 4]);

        f32x16 init;
        init[0]  = lo16f(nw0.x); init[1]  = hi16f(nw0.x);
        init[2]  = lo16f(nw0.y); init[3]  = hi16f(nw0.y);
        init[4]  = lo16f(nw0.z); init[5]  = hi16f(nw0.z);
        init[6]  = lo16f(nw0.w); init[7]  = hi16f(nw0.w);
        init[8]  = lo16f(nw1.x); init[9]  = hi16f(nw1.x);
        init[10] = lo16f(nw1.y); init[11] = hi16f(nw1.y);
        init[12] = lo16f(nw1.z); init[13] = hi16f(nw1.z);
        init[14] = lo16f(nw1.w); init[15] = hi16f(nw1.w);

        f32x16 a0 = __builtin_amdgcn_mfma_f32_32x32x16_f16(A1.v, Bf[0][0].v, init, 0, 0, 0);
        a0        = __builtin_amdgcn_mfma_f32_32x32x16_f16(A2.v, Bf[0][1].v, a0,   0, 0, 0);
        f32x16 a1 = __builtin_amdgcn_mfma_f32_32x32x16_f16(A1.v, Bf[1][0].v, init, 0, 0, 0);
        a1        = __builtin_amdgcn_mfma_f32_32x32x16_f16(A2.v, Bf[1][1].v, a1,   0, 0, 0);

        #pragma unroll
        for (int e = 0; e < 16; ++e) rmax[0][e] = fmaxf(rmax[0][e], a0[e]);
        #pragma unroll
        for (int e = 0; e < 16; ++e) rmax[1][e] = fmaxf(rmax[1][e], a1[e]);
    }

    // --- epilogue: in-wave shuffles only ---
    float p0v = 0.0f, p1v = 0.0f;
    #pragma unroll
    for (int lt = 0; lt < 2; ++lt) {
        float m = rmax[lt][0];
        #pragma unroll
        for (int e = 1; e < 16; ++e) m = fmaxf(m, rmax[lt][e]);
        m = fmaxf(m, __shfl_xor(m, 32, 64));          // other 4h' row group
        float sq = ssq[lt] + __shfl_xor(ssq[lt], 32, 64);  // full 32-k sum
        float f = (sq - 2.0f * m) * (1.0f / (float)KLEN);  // min dist, shapelet lt*32+l31
        p0v = fmaf(f, fc_w[lt * 32 + l31], p0v);
        p1v = fmaf(f, fc_w[NL + lt * 32 + l31], p1v);
    }
    #pragma unroll
    for (int off = 1; off <= 16; off <<= 1) {
        p0v += __shfl_xor(p0v, off, 64);
        p1v += __shfl_xor(p1v, off, 64);
    }
    if (lane == 0) {
        out[(size_t)row * 2 + 0] = p0v + fc_b[0];
        out[(size_t)row * 2 + 1] = p1v + fc_b[1];
    }
}

extern "C" void kernel_launch(void* const* d_in, const int* in_sizes, int n_in,
                              void* d_out, int out_size, void* d_ws, size_t ws_size,
                              hipStream_t stream) {
    const float* ts        = (const float*)d_in[0];
    const float* shapelets = (const float*)d_in[1];
    const float* fc_w      = (const float*)d_in[2];
    const float* fc_b      = (const float*)d_in[3];
    float* out = (float*)d_out;

    shapelet_r20<<<NB / 4, 256, 0, stream>>>(ts, shapelets, fc_w, fc_b, out);
}

// Round 21
// 38.841 us; speedup vs baseline: 1.0077x; 1.0077x over previous
//
#include <hip/hip_runtime.h>
#include <stdint.h>

#define NB 4096
#define QLEN 1024
#define NL 64
#define KLEN 32
#define NS (QLEN - KLEN + 1)   // 993
#define WSLICE 1864            // u32: pkE 544 | pkO 544 | nwh 512 | s4 264 (7.46 KB)

typedef __attribute__((ext_vector_type(8)))  _Float16 half8;
typedef __attribute__((ext_vector_type(16))) float    f32x16;

union frag4 { uint4 q; half8 v; uint32_t u[4]; };

static __device__ __forceinline__ uint32_t pkh(float a, float b) {
    return __builtin_bit_cast(uint32_t, __builtin_amdgcn_cvt_pkrtz(a, b)); // v_cvt_pkrtz_f16_f32
}
static __device__ __forceinline__ float lo16f(uint32_t w) {
    return (float)__builtin_bit_cast(_Float16, (unsigned short)(w & 0xFFFFu));
}
static __device__ __forceinline__ float hi16f(uint32_t w) {
    return (float)__builtin_bit_cast(_Float16, (unsigned short)(w >> 16));
}
static __device__ __forceinline__ uint32_t pkh_rne(float a, float b) {  // RNE f16 pair
    unsigned short ha = __builtin_bit_cast(unsigned short, (_Float16)a);
    unsigned short hb = __builtin_bit_cast(unsigned short, (_Float16)b);
    return (uint32_t)ha | ((uint32_t)hb << 16);
}

__global__ __launch_bounds__(64, 2) void shapelet_r21(
    const float* __restrict__ ts,        // [B, Q]
    const float* __restrict__ shapelets, // [L, K]
    const float* __restrict__ fc_w,      // [2, L]
    const float* __restrict__ fc_b,      // [2]
    float* __restrict__ out)             // [B, 2]
{
    // 1 wave = 1 block = 1 row; 16 blocks/CU; no __syncthreads anywhere.
    __shared__ __align__(16) uint32_t lds[WSLICE];

    const int lane = threadIdx.x & 63;
    const int l31  = lane & 31;          // shapelet / A-row index
    const int hk   = lane >> 5;          // k-half-group (0,1)
    const int row  = blockIdx.x;

    uint32_t* pkE = lds;                                   // [544]
    uint32_t* pkO = pkE + 544;                             // [544]
    uint32_t* nwh = pkO + 544;                             // [512] -0.5*win f16, permuted
    float*    s4  = reinterpret_cast<float*>(nwh + 512);   // [264]

    // --- pass 1: load row, pack f16 phase-pairs, 4-square partials ---
    const float* rowp = ts + (size_t)row * QLEN;
    float4 v[4];
    float  x4[4];
    #pragma unroll
    for (int c = 0; c < 4; ++c)
        v[c] = reinterpret_cast<const float4*>(rowp)[64 * c + lane];
    #pragma unroll
    for (int c = 0; c < 4; ++c) {
        const int p = 256 * c + 4 * lane + 4;
        x4[c] = (p < QLEN) ? rowp[p] : 0.0f;
    }
    #pragma unroll
    for (int c = 0; c < 4; ++c) {
        uint2 pe = { pkh(v[c].x, v[c].y), pkh(v[c].z, v[c].w) };
        uint2 po = { pkh(v[c].y, v[c].z), pkh(v[c].w, x4[c]) };
        reinterpret_cast<uint2*>(pkE)[64 * c + lane] = pe;
        reinterpret_cast<uint2*>(pkO)[64 * c + lane] = po;
        s4[64 * c + lane] =
            fmaf(v[c].x, v[c].x, fmaf(v[c].y, v[c].y, fmaf(v[c].z, v[c].z, v[c].w * v[c].w)));
    }
    if (lane < 32) { pkE[512 + lane] = 0u; pkO[512 + lane] = 0u; }
    if (lane < 8)  s4[256 + lane] = 0.0f;

    // --- B fragments (fp16 RTZ), 32x32x16 layout (same as r20, refcheck'd) ---
    frag4 Bf[2][2];   // [lt][kh]
    float ssq[2];
    #pragma unroll
    for (int lt = 0; lt < 2; ++lt) {
        float s = 0.0f;
        #pragma unroll
        for (int kh = 0; kh < 2; ++kh) {
            const float* sp = shapelets + (lt * 32 + l31) * KLEN + kh * 16 + hk * 8;
            float4 f0 = *reinterpret_cast<const float4*>(sp);
            float4 f1 = *reinterpret_cast<const float4*>(sp + 4);
            Bf[lt][kh].u[0] = pkh(f0.x, f0.y);
            Bf[lt][kh].u[1] = pkh(f0.z, f0.w);
            Bf[lt][kh].u[2] = pkh(f1.x, f1.y);
            Bf[lt][kh].u[3] = pkh(f1.z, f1.w);
            s = fmaf(f0.x, f0.x, s); s = fmaf(f0.y, f0.y, s);
            s = fmaf(f0.z, f0.z, s); s = fmaf(f0.w, f0.w, s);
            s = fmaf(f1.x, f1.x, s); s = fmaf(f1.y, f1.y, s);
            s = fmaf(f1.z, f1.z, s); s = fmaf(f1.w, f1.w, s);
        }
        ssq[lt] = s;   // half of 32 k; other half in lane^32
    }

    __builtin_amdgcn_wave_barrier();   // pass-1 writes before pass-2 reads

    // --- pass 2: win_sq + f16 corrections -> nwh in 32x32 C-layout order ---
    #pragma unroll
    for (int c = 0; c < 4; ++c) {
        const int q = 64 * c + lane;
        float s_[8];
        #pragma unroll
        for (int j = 0; j < 8; ++j) s_[j] = s4[q + j];
        float w0 = ((s_[0] + s_[1]) + (s_[2] + s_[3])) + ((s_[4] + s_[5]) + (s_[6] + s_[7]));
        uint32_t cw0 = pkE[2 * (q + 8)];
        uint32_t cw1 = pkE[2 * (q + 8) + 1];
        float x32 = lo16f(cw0), x33 = hi16f(cw0), x34 = lo16f(cw1);
        float w1 = fmaf(x32, x32, fmaf(-v[c].x, v[c].x, w0));
        float w2 = fmaf(x33, x33, fmaf(-v[c].y, v[c].y, w1));
        float w3 = fmaf(x34, x34, fmaf(-v[c].z, v[c].z, w2));
        const int p0 = 4 * q;
        float c0 = (p0 + 0 < NS) ? -0.5f * w0 : -60000.0f;
        float c1 = (p0 + 1 < NS) ? -0.5f * w1 : -60000.0f;
        float c2 = (p0 + 2 < NS) ? -0.5f * w2 : -60000.0f;
        float c3 = (p0 + 3 < NS) ? -0.5f * w3 : -60000.0f;
        const int W = 16 * (p0 >> 5) + ((p0 >> 2) & 1) * 8 + ((p0 >> 3) & 3) * 2;
        uint2 hw = { pkh_rne(c0, c1), pkh_rne(c2, c3) };
        *reinterpret_cast<uint2*>(&nwh[W]) = hw;
    }

    __builtin_amdgcn_wave_barrier();   // pass-2 stores before main-loop reads

    // --- main loop: 32 position-tiles; sequential-lt to keep the live set
    //     in arch VGPRs (r20's AGPR-shuttle/spill fix) ---
    float rmax0[16], rmax1[16];
    #pragma unroll
    for (int e = 0; e < 16; ++e) { rmax0[e] = -3.0e38f; rmax1[e] = -3.0e38f; }

    const int par = l31 & 1;
    const uint32_t* apk = (par ? pkO : pkE) + (((l31 - par) >> 1) + hk * 4);
    const int nwb = hk * 8;

    #pragma unroll 1
    for (int t = 0; t < 32; ++t) {
        const uint32_t* ap = apk + 16 * t;
        frag4 A1, A2;
        #pragma unroll
        for (int j = 0; j < 4; ++j) A1.u[j] = ap[j];
        #pragma unroll
        for (int j = 0; j < 4; ++j) A2.u[j] = ap[8 + j];
        uint4 nw0 = *reinterpret_cast<const uint4*>(&nwh[16 * t + nwb]);
        uint4 nw1 = *reinterpret_cast<const uint4*>(&nwh[16 * t + nwb + 4]);

        f32x16 init;
        init[0]  = lo16f(nw0.x); init[1]  = hi16f(nw0.x);
        init[2]  = lo16f(nw0.y); init[3]  = hi16f(nw0.y);
        init[4]  = lo16f(nw0.z); init[5]  = hi16f(nw0.z);
        init[6]  = lo16f(nw0.w); init[7]  = hi16f(nw0.w);
        init[8]  = lo16f(nw1.x); init[9]  = hi16f(nw1.x);
        init[10] = lo16f(nw1.y); init[11] = hi16f(nw1.y);
        init[12] = lo16f(nw1.z); init[13] = hi16f(nw1.z);
        init[14] = lo16f(nw1.w); init[15] = hi16f(nw1.w);

        f32x16 a0 = __builtin_amdgcn_mfma_f32_32x32x16_f16(A1.v, Bf[0][0].v, init, 0, 0, 0);
        a0        = __builtin_amdgcn_mfma_f32_32x32x16_f16(A2.v, Bf[0][1].v, a0,   0, 0, 0);
        #pragma unroll
        for (int e = 0; e < 16; ++e) rmax0[e] = fmaxf(rmax0[e], a0[e]);

        f32x16 a1 = __builtin_amdgcn_mfma_f32_32x32x16_f16(A1.v, Bf[1][0].v, init, 0, 0, 0);
        a1        = __builtin_amdgcn_mfma_f32_32x32x16_f16(A2.v, Bf[1][1].v, a1,   0, 0, 0);
        #pragma unroll
        for (int e = 0; e < 16; ++e) rmax1[e] = fmaxf(rmax1[e], a1[e]);
    }

    // --- epilogue: in-wave shuffles only ---
    float p0v = 0.0f, p1v = 0.0f;
    #pragma unroll
    for (int lt = 0; lt < 2; ++lt) {
        const float* rm = lt ? rmax1 : rmax0;
        float m = rm[0];
        #pragma unroll
        for (int e = 1; e < 16; ++e) m = fmaxf(m, rm[e]);
        m = fmaxf(m, __shfl_xor(m, 32, 64));               // other row-half group
        float sq = ssq[lt] + __shfl_xor(ssq[lt], 32, 64);  // full 32-k sum
        float f = (sq - 2.0f * m) * (1.0f / (float)KLEN);  // min dist, shapelet lt*32+l31
        p0v = fmaf(f, fc_w[lt * 32 + l31], p0v);
        p1v = fmaf(f, fc_w[NL + lt * 32 + l31], p1v);
    }
    #pragma unroll
    for (int off = 1; off <= 16; off <<= 1) {
        p0v += __shfl_xor(p0v, off, 64);
        p1v += __shfl_xor(p1v, off, 64);
    }
    if (lane == 0) {
        out[(size_t)row * 2 + 0] = p0v + fc_b[0];
        out[(size_t)row * 2 + 1] = p1v + fc_b[1];
    }
}

extern "C" void kernel_launch(void* const* d_in, const int* in_sizes, int n_in,
                              void* d_out, int out_size, void* d_ws, size_t ws_size,
                              hipStream_t stream) {
    const float* ts        = (const float*)d_in[0];
    const float* shapelets = (const float*)d_in[1];
    const float* fc_w      = (const float*)d_in[2];
    const float* fc_b      = (const float*)d_in[3];
    float* out = (float*)d_out;

    shapelet_r21<<<NB, 64, 0, stream>>>(ts, shapelets, fc_w, fc_b, out);
}

// Round 22
// 23.553 us; speedup vs baseline: 1.6618x; 1.6491x over previous
//
#include <hip/hip_runtime.h>
#include <stdint.h>

#define NB 4096
#define QLEN 1024
#define NL 64
#define KLEN 32
#define NS (QLEN - KLEN + 1)   // 993
#define WSLICE 1856            // u32 per wave LDS slice

typedef __attribute__((ext_vector_type(8))) _Float16 half8;
typedef __attribute__((ext_vector_type(4))) float f32x4;

union fragh { uint32_t u[4]; half8 v; };

static __device__ __forceinline__ uint32_t pkh(float a, float b) {
    return __builtin_bit_cast(uint32_t, __builtin_amdgcn_cvt_pkrtz(a, b)); // v_cvt_pkrtz_f16_f32
}
static __device__ __forceinline__ float lo16f(uint32_t w) {
    return (float)__builtin_bit_cast(_Float16, (unsigned short)(w & 0xFFFFu));
}
static __device__ __forceinline__ float hi16f(uint32_t w) {
    return (float)__builtin_bit_cast(_Float16, (unsigned short)(w >> 16));
}
static __device__ __forceinline__ uint32_t pkh_rne(float a, float b) {  // RNE f16 pair
    unsigned short ha = __builtin_bit_cast(unsigned short, (_Float16)a);
    unsigned short hb = __builtin_bit_cast(unsigned short, (_Float16)b);
    return (uint32_t)ha | ((uint32_t)hb << 16);
}

__global__ __launch_bounds__(256, 4) void shapelet_r22(
    const float* __restrict__ ts,        // [B, Q]
    const float* __restrict__ shapelets, // [L, K]
    const float* __restrict__ fc_w,      // [2, L]
    const float* __restrict__ fc_b,      // [2]
    float* __restrict__ out)             // [B, 2]
{
    // 4 private slices, one per wave; NO __syncthreads in this kernel.
    __shared__ __align__(16) uint32_t lds[4 * WSLICE];   // 29.7 KB

    const int tid  = threadIdx.x;
    const int wave = tid >> 6;
    const int lane = tid & 63;
    const int col  = lane & 15;
    const int kg   = lane >> 4;
    const int row  = blockIdx.x * 4 + wave;   // this wave's batch row

    uint32_t* pkE = lds + wave * WSLICE;                   // [528]
    uint32_t* pkO = pkE + 528;                             // [528]
    uint32_t* nwh = pkO + 528;                             // [512]
    float*    s4  = reinterpret_cast<float*>(nwh + 512);   // [264]

    // --- pass 1: wave loads its whole row (4 float4/lane), packs, partials ---
    const float* rowp = ts + (size_t)row * QLEN;
    float4 v[4];
    #pragma unroll
    for (int c = 0; c < 4; ++c)
        v[c] = reinterpret_cast<const float4*>(rowp)[64 * c + lane];
    float x4[4];
    #pragma unroll
    for (int c = 0; c < 4; ++c) {
        const int p = 256 * c + 4 * lane + 4;
        x4[c] = (p < QLEN) ? rowp[p] : 0.0f;
    }
    #pragma unroll
    for (int c = 0; c < 4; ++c) {
        uint2 pe = { pkh(v[c].x, v[c].y), pkh(v[c].z, v[c].w) };
        uint2 po = { pkh(v[c].y, v[c].z), pkh(v[c].w, x4[c]) };
        reinterpret_cast<uint2*>(pkE)[64 * c + lane] = pe;
        reinterpret_cast<uint2*>(pkO)[64 * c + lane] = po;
        s4[64 * c + lane] =
            fmaf(v[c].x, v[c].x, fmaf(v[c].y, v[c].y, fmaf(v[c].z, v[c].z, v[c].w * v[c].w)));
    }
    if (lane < 16) { pkE[512 + lane] = 0u; pkO[512 + lane] = 0u; }
    if (lane < 8)  s4[256 + lane] = 0.0f;

    // --- B fragments (fp16 RTZ) + exact fp32 ssq partials ---
    fragh Bh[4];
    float ssq[4];
    #pragma unroll
    for (int lt = 0; lt < 4; ++lt) {
        const float* sp = shapelets + (lt * 16 + col) * KLEN + kg * 8;
        float4 f0 = *reinterpret_cast<const float4*>(sp);
        float4 f1 = *reinterpret_cast<const float4*>(sp + 4);
        Bh[lt].u[0] = pkh(f0.x, f0.y);
        Bh[lt].u[1] = pkh(f0.z, f0.w);
        Bh[lt].u[2] = pkh(f1.x, f1.y);
        Bh[lt].u[3] = pkh(f1.z, f1.w);
        float s = f0.x * f0.x;
        s = fmaf(f0.y, f0.y, s); s = fmaf(f0.z, f0.z, s); s = fmaf(f0.w, f0.w, s);
        s = fmaf(f1.x, f1.x, s); s = fmaf(f1.y, f1.y, s);
        s = fmaf(f1.z, f1.z, s); s = fmaf(f1.w, f1.w, s);
        ssq[lt] = s;   // kg-partial; reduced in epilogue
    }

    __builtin_amdgcn_wave_barrier();   // order pass-1 LDS writes before pass-2 reads

    // --- pass 2: win_sq from s4 partials + f16 sliding corrections -> nwh ---
    #pragma unroll
    for (int c = 0; c < 4; ++c) {
        const int q = 64 * c + lane;
        float s_[8];
        #pragma unroll
        for (int j = 0; j < 8; ++j) s_[j] = s4[q + j];
        float w0 = ((s_[0] + s_[1]) + (s_[2] + s_[3])) + ((s_[4] + s_[5]) + (s_[6] + s_[7]));
        uint32_t cw0 = pkE[2 * (q + 8)];
        uint32_t cw1 = pkE[2 * (q + 8) + 1];
        float x32 = lo16f(cw0), x33 = hi16f(cw0), x34 = lo16f(cw1);
        float w1 = fmaf(x32, x32, fmaf(-v[c].x, v[c].x, w0));
        float w2 = fmaf(x33, x33, fmaf(-v[c].y, v[c].y, w1));
        float w3 = fmaf(x34, x34, fmaf(-v[c].z, v[c].z, w2));
        const int p0 = 4 * q;
        float c0 = (p0 + 0 < NS) ? -0.5f * w0 : -60000.0f;
        float c1 = (p0 + 1 < NS) ? -0.5f * w1 : -60000.0f;
        float c2 = (p0 + 2 < NS) ? -0.5f * w2 : -60000.0f;
        float c3 = (p0 + 3 < NS) ? -0.5f * w3 : -60000.0f;
        const int qq = p0 & 31;
        const int W = ((p0 >> 5) << 4) + (((qq & 15) >> 2) << 2) + ((qq >> 4) << 1);
        uint2 hw = { pkh_rne(c0, c1), pkh_rne(c2, c3) };
        *reinterpret_cast<uint2*>(&nwh[W]) = hw;
    }

    __builtin_amdgcn_wave_barrier();   // order pass-2 stores before main-loop reads

    // --- main loop: 16 bodies x 2 tile-pairs; ALL loads+cvts at body top
    //     (one lgkmcnt point per 2 iters; 16 back-to-back MFMAs follow).
    //     Straight-line SSA: no conditionals, no rotation (r6/r8 spill-safe). ---
    float rmax[4][4];
    #pragma unroll
    for (int lt = 0; lt < 4; ++lt)
        #pragma unroll
        for (int e = 0; e < 4; ++e) rmax[lt][e] = -3.0e38f;

    const int par = col & 1;
    const uint32_t* apk = (par ? pkO : pkE) + (((col - par) >> 1) + kg * 4);
    const int nwb = 4 * kg;

    #pragma unroll 1
    for (int p = 0; p < 16; ++p) {
        const uint32_t* ap0 = apk + 32 * p;
        const uint32_t* ap1 = apk + 32 * p + 16;

        // -- all 6 LDS reads --
        fragh Aa0, Ab0, Aa1, Ab1;
        #pragma unroll
        for (int j = 0; j < 4; ++j) Aa0.u[j] = ap0[j];
        #pragma unroll
        for (int j = 0; j < 4; ++j) Ab0.u[j] = ap0[8 + j];
        #pragma unroll
        for (int j = 0; j < 4; ++j) Aa1.u[j] = ap1[j];
        #pragma unroll
        for (int j = 0; j < 4; ++j) Ab1.u[j] = ap1[8 + j];
        uint4 nw0 = *reinterpret_cast<const uint4*>(&nwh[32 * p + nwb]);
        uint4 nw1 = *reinterpret_cast<const uint4*>(&nwh[32 * p + 16 + nwb]);

        // -- all 16 cvts --
        f32x4 ia0, ib0, ia1, ib1;
        ia0[0] = lo16f(nw0.x); ia0[1] = hi16f(nw0.x);
        ia0[2] = lo16f(nw0.y); ia0[3] = hi16f(nw0.y);
        ib0[0] = lo16f(nw0.z); ib0[1] = hi16f(nw0.z);
        ib0[2] = lo16f(nw0.w); ib0[3] = hi16f(nw0.w);
        ia1[0] = lo16f(nw1.x); ia1[1] = hi16f(nw1.x);
        ia1[2] = lo16f(nw1.y); ia1[3] = hi16f(nw1.y);
        ib1[0] = lo16f(nw1.z); ib1[1] = hi16f(nw1.z);
        ib1[2] = lo16f(nw1.w); ib1[3] = hi16f(nw1.w);

        // -- 16 MFMAs + 32 max3 --
        #pragma unroll
        for (int lt = 0; lt < 4; ++lt) {
            f32x4 aa0 = __builtin_amdgcn_mfma_f32_16x16x32_f16(Aa0.v, Bh[lt].v, ia0, 0, 0, 0);
            f32x4 ab0 = __builtin_amdgcn_mfma_f32_16x16x32_f16(Ab0.v, Bh[lt].v, ib0, 0, 0, 0);
            f32x4 aa1 = __builtin_amdgcn_mfma_f32_16x16x32_f16(Aa1.v, Bh[lt].v, ia1, 0, 0, 0);
            f32x4 ab1 = __builtin_amdgcn_mfma_f32_16x16x32_f16(Ab1.v, Bh[lt].v, ib1, 0, 0, 0);
            #pragma unroll
            for (int e = 0; e < 4; ++e) {
                rmax[lt][e] = fmaxf(fmaxf(aa0[e], ab0[e]), rmax[lt][e]);  // v_max3_f32
                rmax[lt][e] = fmaxf(fmaxf(aa1[e], ab1[e]), rmax[lt][e]);  // v_max3_f32
            }
        }
    }

    // --- epilogue: all in-wave shuffles, no LDS, no barrier ---
    float p0v = 0.0f, p1v = 0.0f;
    #pragma unroll
    for (int lt = 0; lt < 4; ++lt) {
        float m = fmaxf(fmaxf(rmax[lt][0], rmax[lt][1]),
                        fmaxf(rmax[lt][2], rmax[lt][3]));
        m = fmaxf(m, __shfl_xor(m, 16, 64));
        m = fmaxf(m, __shfl_xor(m, 32, 64));
        float sq = ssq[lt];
        sq += __shfl_xor(sq, 16, 64);
        sq += __shfl_xor(sq, 32, 64);
        float f = (sq - 2.0f * m) * (1.0f / (float)KLEN);   // min dist
        p0v = fmaf(f, fc_w[lt * 16 + col], p0v);
        p1v = fmaf(f, fc_w[NL + lt * 16 + col], p1v);
    }
    #pragma unroll
    for (int off = 1; off <= 8; off <<= 1) {
        p0v += __shfl_xor(p0v, off, 64);
        p1v += __shfl_xor(p1v, off, 64);
    }
    if (lane == 0) {
        out[(size_t)row * 2 + 0] = p0v + fc_b[0];
        out[(size_t)row * 2 + 1] = p1v + fc_b[1];
    }
}

extern "C" void kernel_launch(void* const* d_in, const int* in_sizes, int n_in,
                              void* d_out, int out_size, void* d_ws, size_t ws_size,
                              hipStream_t stream) {
    const float* ts        = (const float*)d_in[0];
    const float* shapelets = (const float*)d_in[1];
    const float* fc_w      = (const float*)d_in[2];
    const float* fc_b      = (const float*)d_in[3];
    float* out = (float*)d_out;

    shapelet_r22<<<NB / 4, 256, 0, stream>>>(ts, shapelets, fc_w, fc_b, out);
}